// Round 1
// baseline (2104.947 us; speedup 1.0000x reference)
//
#include <hip/hip_runtime.h>

#define MB 4
#define CC 3
#define MM 192
#define NN 192
#define PP 32
#define KITER 8
#define MN (MM*NN)          /* 36864  */
#define CMN (CC*MN)         /* 110592 */
#define IMG (MB*CMN)        /* 442368 */
#define ASZ (MB*PP*CMN)     /* 14155776 */

#define S3 0.57735026918962576f
#define S2 0.70710678118654752f
#define S6 0.40824829046386302f
#define W_CH 0.8f
#define EPSV 1e-8f
#define RADIUS 6.6510751010644885f   /* 0.02*sqrt(3*192*192) */

#define TDIM 32
#define HT 38       /* tile + 6 halo */
#define HS 40       /* padded LDS row stride (16B-aligned rows) */

__device__ __forceinline__ float softf(float x, float t) {
    float m = fabsf(x) - t;
    return m > 0.f ? copysignf(m, x) : 0.f;
}

// r = x_bef - conv_csc(a, B)
__global__ __launch_bounds__(256) void k_conv_r(
    const float* __restrict__ a, const float* __restrict__ xbef,
    const float* __restrict__ Bw, float* __restrict__ r)
{
    const int b = blockIdx.z / CC, c = blockIdx.z % CC;
    const int m0 = blockIdx.y * TDIM, n0 = blockIdx.x * TDIM;
    __shared__ float sT[HT * HS];
    const int row = threadIdx.x >> 3;      // 0..31
    const int tg  = threadIdx.x & 7;       // 0..7 -> cols tg*4..tg*4+3
    float acc[4] = {0.f, 0.f, 0.f, 0.f};
    const float* Bc = Bw + c * 49;
    for (int p = 0; p < PP; ++p) {
        __syncthreads();
        const float* ap = a + (size_t)((b*PP + p)*CC + c) * MN;
        for (int i = threadIdx.x; i < HT*HT; i += 256) {
            int im = i / HT, in = i - im*HT;
            int gm = m0 + im - 3, gn = n0 + in - 3;
            float v = 0.f;
            if ((unsigned)gm < MM && (unsigned)gn < NN) v = ap[gm*NN + gn];
            sT[im*HS + in] = v;
        }
        __syncthreads();
        const float* bp = Bc + p * (CC*49);
        #pragma unroll
        for (int u = 0; u < 7; ++u) {
            const int base = (row + u)*HS + tg*4;
            const float4 q0 = *(const float4*)&sT[base];
            const float4 q1 = *(const float4*)&sT[base + 4];
            const float2 q2 = *(const float2*)&sT[base + 8];
            const float rv[10] = {q0.x,q0.y,q0.z,q0.w,q1.x,q1.y,q1.z,q1.w,q2.x,q2.y};
            #pragma unroll
            for (int v = 0; v < 7; ++v) {
                const float bv = bp[u*7 + v];
                acc[0] += rv[v]   * bv;
                acc[1] += rv[v+1] * bv;
                acc[2] += rv[v+2] * bv;
                acc[3] += rv[v+3] * bv;
            }
        }
    }
    const int gm = m0 + row;
    const int idx = (b*CC + c)*MN + gm*NN + n0 + tg*4;
    const float4 xv = *(const float4*)&xbef[idx];
    float4 o;
    o.x = xv.x - acc[0]; o.y = xv.y - acc[1];
    o.z = xv.z - acc[2]; o.w = xv.w - acc[3];
    *(float4*)&r[idx] = o;
}

// a_out = soft(a_in + g2 * convT_csc(r, B), g2*lam1)   (in-place safe)
__global__ __launch_bounds__(256) void k_a_update(
    const float* __restrict__ a_in, const float* __restrict__ rr,
    const float* __restrict__ Bw, float* __restrict__ a_out,
    const float* __restrict__ gam2, const float* __restrict__ lam1, int k)
{
    const int b = blockIdx.z / CC, c = blockIdx.z % CC;
    const int m0 = blockIdx.y * TDIM, n0 = blockIdx.x * TDIM;
    const float g2  = gam2[k];
    const float thr = g2 * lam1[k];
    __shared__ float sT[HT * HS];
    const float* rp = rr + (b*CC + c)*MN;
    for (int i = threadIdx.x; i < HT*HT; i += 256) {
        int im = i / HT, in = i - im*HT;
        int gm = m0 + im - 3, gn = n0 + in - 3;
        float v = 0.f;
        if ((unsigned)gm < MM && (unsigned)gn < NN) v = rp[gm*NN + gn];
        sT[im*HS + in] = v;
    }
    __syncthreads();
    const int row = threadIdx.x >> 3;
    const int tg  = threadIdx.x & 7;
    const int gm = m0 + row;
    const int gn = n0 + tg*4;
    const float* Bc = Bw + c * 49;
    for (int p = 0; p < PP; ++p) {
        const float* bp = Bc + p * (CC*49);
        float acc[4] = {0.f, 0.f, 0.f, 0.f};
        #pragma unroll
        for (int u = 0; u < 7; ++u) {
            const int base = (row + 6 - u)*HS + tg*4;
            const float4 q0 = *(const float4*)&sT[base];
            const float4 q1 = *(const float4*)&sT[base + 4];
            const float2 q2 = *(const float2*)&sT[base + 8];
            const float rv[10] = {q0.x,q0.y,q0.z,q0.w,q1.x,q1.y,q1.z,q1.w,q2.x,q2.y};
            #pragma unroll
            for (int v = 0; v < 7; ++v) {
                const float bv = bp[u*7 + v];
                acc[0] += rv[6-v]   * bv;
                acc[1] += rv[7-v]   * bv;
                acc[2] += rv[8-v]   * bv;
                acc[3] += rv[9-v]   * bv;
            }
        }
        const size_t idx = (size_t)((b*PP + p)*CC + c)*MN + gm*NN + gn;
        const float4 av = *(const float4*)&a_in[idx];
        float4 o;
        o.x = softf(av.x + g2*acc[0], thr);
        o.y = softf(av.y + g2*acc[1], thr);
        o.z = softf(av.z + g2*acc[2], thr);
        o.w = softf(av.w + g2*acc[3], thr);
        *(float4*)&a_out[idx] = o;
    }
}

// x_aft = clip(x_bef - g1*(r + Ctop(Dtop(y1)) + mask*y2), 0, 1)
__global__ __launch_bounds__(256) void k_x_update(
    const float* __restrict__ xbef, const float* __restrict__ rr,
    const float* __restrict__ y1, const float* __restrict__ y2,
    const float* __restrict__ mask, const float* __restrict__ gam1, int k,
    float* __restrict__ xaft)
{
    const int i = blockIdx.x*256 + threadIdx.x;
    if (i >= MB*MN) return;
    const int b = i / MN, mn = i - b*MN;
    const int m = mn / NN, n = mn - m*NN;
    const float g1 = gam1[k];
    float dt[3];
    #pragma unroll
    for (int e = 0; e < 3; ++e) {
        const float* yv = y1 + ((size_t)(b*2 + 0)*CC + e)*MN;
        const float* yh = y1 + ((size_t)(b*2 + 1)*CC + e)*MN;
        // Dtop: dv = yv'[m-1,n] - yv'[m,n], yv' has row M-1 zeroed (similarly yh cols)
        float dv = (m > 0      ? yv[mn - NN] : 0.f) - (m < MM-1 ? yv[mn] : 0.f);
        float dh = (n > 0      ? yh[mn - 1]  : 0.f) - (n < NN-1 ? yh[mn] : 0.f);
        dt[e] = dv + dh;
    }
    // Ctop: out[c] = sum_e CMAT[e][c]*dt[e]
    const float ct0 = S3*dt[0] + S2*dt[1] + S6*dt[2];
    const float ct1 = S3*dt[0] - S2*dt[1] + S6*dt[2];
    const float ct2 = S3*dt[0]            - 2.f*S6*dt[2];
    const float ct[3] = {ct0, ct1, ct2};
    #pragma unroll
    for (int c = 0; c < 3; ++c) {
        const int idx = (b*CC + c)*MN + mn;
        float x = xbef[idx] - g1*(rr[idx] + ct[c] + mask[idx]*y2[idx]);
        x = fminf(fmaxf(x, 0.f), 1.f);
        xaft[idx] = x;
    }
}

// y1 += g3*Dop(Cop(v)); y1 = y1 - g3*prox_dvtv(y1/(g3+eps), lam2/(g3+eps), w)   (in-place)
__global__ __launch_bounds__(256) void k_y1_update(
    float* __restrict__ y1, const float* __restrict__ xaft,
    const float* __restrict__ xbef,
    const float* __restrict__ gam3, const float* __restrict__ lam2, int k)
{
    const int i = blockIdx.x*256 + threadIdx.x;
    if (i >= MB*MN) return;
    const int b = i / MN, mn = i - b*MN;
    const int m = mn / NN, n = mn - m*NN;
    const float g3  = gam3[k];
    const float inv = 1.f / (g3 + EPSV);
    const float t   = lam2[k] * inv;
    const bool hasD = (m < MM-1), hasR = (n < NN-1);
    float vc[3], vd[3], vr[3];
    #pragma unroll
    for (int c = 0; c < 3; ++c) {
        const int idx = (b*CC + c)*MN + mn;
        vc[c] = 2.f*xaft[idx] - xbef[idx];
        vd[c] = hasD ? (2.f*xaft[idx+NN] - xbef[idx+NN]) : 0.f;
        vr[c] = hasR ? (2.f*xaft[idx+1]  - xbef[idx+1])  : 0.f;
    }
    // Cop: out[e] = sum_c CMAT[e][c] * v[c]
    const float cc0 = S3*(vc[0]+vc[1]+vc[2]);
    const float cc1 = S2*(vc[0]-vc[1]);
    const float cc2 = S6*(vc[0]+vc[1]) - 2.f*S6*vc[2];
    const float cd0 = S3*(vd[0]+vd[1]+vd[2]);
    const float cd1 = S2*(vd[0]-vd[1]);
    const float cd2 = S6*(vd[0]+vd[1]) - 2.f*S6*vd[2];
    const float cr0 = S3*(vr[0]+vr[1]+vr[2]);
    const float cr1 = S2*(vr[0]-vr[1]);
    const float cr2 = S6*(vr[0]+vr[1]) - 2.f*S6*vr[2];
    const float dv[3] = { hasD ? cd0-cc0 : 0.f, hasD ? cd1-cc1 : 0.f, hasD ? cd2-cc2 : 0.f };
    const float dh[3] = { hasR ? cr0-cc0 : 0.f, hasR ? cr1-cc1 : 0.f, hasR ? cr2-cc2 : 0.f };
    float yn[2][3], vv[2][3];
    #pragma unroll
    for (int e = 0; e < 3; ++e) {
        const int i0 = ((b*2 + 0)*CC + e)*MN + mn;
        const int i1 = ((b*2 + 1)*CC + e)*MN + mn;
        yn[0][e] = y1[i0] + g3*dv[e];
        yn[1][e] = y1[i1] + g3*dh[e];
        vv[0][e] = yn[0][e]*inv;
        vv[1][e] = yn[1][e]*inv;
    }
    const float nl = sqrtf(vv[0][0]*vv[0][0] + vv[1][0]*vv[1][0]);
    const float sl = fmaxf(0.f, 1.f - t / fmaxf(nl, 1e-12f));
    const float nc = sqrtf(vv[0][1]*vv[0][1] + vv[0][2]*vv[0][2]
                         + vv[1][1]*vv[1][1] + vv[1][2]*vv[1][2]);
    const float sc = fmaxf(0.f, 1.f - t*W_CH / fmaxf(nc, 1e-12f));
    #pragma unroll
    for (int e = 0; e < 3; ++e) {
        const float se = (e == 0) ? sl : sc;
        const int i0 = ((b*2 + 0)*CC + e)*MN + mn;
        const int i1 = ((b*2 + 1)*CC + e)*MN + mn;
        y1[i0] = yn[0][e] - g3*(vv[0][e]*se);
        y1[i1] = yn[1][e] - g3*(vv[1][e]*se);
    }
}

// y2 += g3*mask*v; accumulate per-batch ||y2/(g3+eps) - z||^2
__global__ __launch_bounds__(256) void k_y2_acc(
    float* __restrict__ y2, const float* __restrict__ xaft,
    const float* __restrict__ xbef, const float* __restrict__ mask,
    const float* __restrict__ z,
    const float* __restrict__ gam3, int k, float* __restrict__ sums)
{
    const int i = blockIdx.x*256 + threadIdx.x;
    const float g3  = gam3[k];
    const float inv = 1.f / (g3 + EPSV);
    float dsq = 0.f;
    if (i < IMG) {
        const float v  = 2.f*xaft[i] - xbef[i];
        const float yn = y2[i] + g3*(mask[i]*v);
        y2[i] = yn;
        const float d = yn*inv - z[i];
        dsq = d*d;
    }
    #pragma unroll
    for (int off = 32; off > 0; off >>= 1) dsq += __shfl_down(dsq, off, 64);
    if ((threadIdx.x & 63) == 0) {
        const int b = blockIdx.x / (CMN/256);   // block fully inside one batch
        atomicAdd(&sums[b], dsq);
    }
}

// y2 -= g3 * proj_l2ball(y2/(g3+eps), z, radius)
__global__ __launch_bounds__(256) void k_y2_proj(
    float* __restrict__ y2, const float* __restrict__ z,
    const float* __restrict__ gam3, int k, const float* __restrict__ sums)
{
    const int i = blockIdx.x*256 + threadIdx.x;
    if (i >= IMG) return;
    const float g3  = gam3[k];
    const float inv = 1.f / (g3 + EPSV);
    const int b = blockIdx.x / (CMN/256);
    const float nrm = sqrtf(sums[b]);
    const float scale = fminf(1.f, RADIUS / fmaxf(nrm, 1e-12f));
    const float zi = z[i];
    const float d = y2[i]*inv - zi;
    y2[i] = y2[i] - g3*(zi + d*scale);
}

extern "C" void kernel_launch(void* const* d_in, const int* in_sizes, int n_in,
                              void* d_out, int out_size, void* d_ws, size_t ws_size,
                              hipStream_t stream) {
    const float* z    = (const float*)d_in[0];
    const float* mask = (const float*)d_in[1];
    const float* a0   = (const float*)d_in[2];
    const float* Bw   = (const float*)d_in[3];
    const float* lam1 = (const float*)d_in[4];
    const float* lam2 = (const float*)d_in[5];
    const float* gam1 = (const float*)d_in[6];
    const float* gam2 = (const float*)d_in[7];
    const float* gam3 = (const float*)d_in[8];
    float* out = (float*)d_out;

    float* ws = (float*)d_ws;
    float* xA   = ws; ws += IMG;
    float* xB   = ws; ws += IMG;
    float* y1   = ws; ws += 2*IMG;
    float* y2   = ws; ws += IMG;
    float* rb   = ws; ws += IMG;
    float* sums = ws; ws += 64;
    const size_t base_need = (size_t)(6*IMG + 64) * sizeof(float);
    float* a_ws;
    if (ws_size >= base_need + (size_t)ASZ * sizeof(float)) {
        a_ws = ws;                    // normal path: a lives in workspace
    } else {
        a_ws = (float*)d_in[2];       // fallback: in-place on a0 (restored per launch)
    }

    hipMemsetAsync(y1, 0, sizeof(float)*2*IMG, stream);
    hipMemsetAsync(y2, 0, sizeof(float)*IMG, stream);

    dim3 gconv(NN/TDIM, MM/TDIM, MB*CC);
    const int ew_blocks  = (MB*MN + 255) / 256;   // 576
    const int img_blocks = IMG / 256;             // 1728

    const float* xbef = z;
    float* xaft = xA;
    const float* acur = a0;
    for (int k = 0; k < KITER; ++k) {
        k_conv_r<<<gconv, 256, 0, stream>>>(acur, xbef, Bw, rb);
        float* xt = (k == KITER-1) ? out : xaft;
        k_x_update<<<ew_blocks, 256, 0, stream>>>(xbef, rb, y1, y2, mask, gam1, k, xt);
        if (k < KITER-1) {
            k_a_update<<<gconv, 256, 0, stream>>>(acur, rb, Bw, a_ws, gam2, lam1, k);
            k_y1_update<<<ew_blocks, 256, 0, stream>>>(y1, xt, xbef, gam3, lam2, k);
            hipMemsetAsync(sums, 0, sizeof(float)*4, stream);
            k_y2_acc<<<img_blocks, 256, 0, stream>>>(y2, xt, xbef, mask, z, gam3, k, sums);
            k_y2_proj<<<img_blocks, 256, 0, stream>>>(y2, z, gam3, k, sums);
            acur = a_ws;
            xbef = xt;
            xaft = (xt == xA) ? xB : xA;
        }
    }
    (void)in_sizes; (void)n_in; (void)out_size;
}

// Round 2
// 1567.357 us; speedup vs baseline: 1.3430x; 1.3430x over previous
//
#include <hip/hip_runtime.h>

#define MB 4
#define CC 3
#define MM 192
#define NN 192
#define PP 32
#define KITER 8
#define MN (MM*NN)          /* 36864  */
#define CMN (CC*MN)         /* 110592 */
#define IMG (MB*CMN)        /* 442368 */
#define ASZ (MB*PP*CMN)     /* 14155776 */

#define PSPLIT 4
#define PCHUNK (PP/PSPLIT)  /* 8 */

#define S3 0.57735026918962576f
#define S2 0.70710678118654752f
#define S6 0.40824829046386302f
#define W_CH 0.8f
#define EPSV 1e-8f
#define RADIUS 6.6510751010644885f   /* 0.02*sqrt(3*192*192) */

#define TDIM 32
#define HT 38       /* tile + 6 halo */
#define HS 40       /* padded LDS row stride */
#define HTT (HT*HT) /* 1444 */

__device__ __forceinline__ float softf(float x, float t) {
    float m = fabsf(x) - t;
    return m > 0.f ? copysignf(m, x) : 0.f;
}

// partial conv: part[s] = sum_{p in chunk s} xcorr(a[b,p,c], B[p,c])
__global__ __launch_bounds__(256) void k_conv_part(
    const float* __restrict__ a, const float* __restrict__ Bw,
    float* __restrict__ part)
{
    const int bc = blockIdx.z % (MB*CC);
    const int s  = blockIdx.z / (MB*CC);
    const int b = bc / CC, c = bc % CC;
    const int m0 = blockIdx.y * TDIM, n0 = blockIdx.x * TDIM;
    __shared__ float sT[HT * HS];
    const int row = threadIdx.x >> 3;      // 0..31
    const int tg  = threadIdx.x & 7;       // 0..7 -> cols tg*4..+3
    float acc[4] = {0.f, 0.f, 0.f, 0.f};
    const int p0 = s * PCHUNK;

    // prefetch indices for staging (each thread loads up to 6 elems)
    int   sidx[6]; float pf[6];
    #pragma unroll
    for (int j = 0; j < 6; ++j) {
        const int i = threadIdx.x + j*256;
        if (i < HTT) {
            const int im = i / HT, in = i - im*HT;
            const int gm = m0 + im - 3, gn = n0 + in - 3;
            sidx[j] = ((unsigned)gm < MM && (unsigned)gn < NN) ? (gm*NN + gn) : -1;
        } else sidx[j] = -2;
    }
    // prefetch p0
    {
        const float* ap = a + (size_t)((b*PP + p0)*CC + c) * MN;
        #pragma unroll
        for (int j = 0; j < 6; ++j)
            if (sidx[j] != -2) pf[j] = (sidx[j] >= 0) ? ap[sidx[j]] : 0.f;
    }
    for (int pp = 0; pp < PCHUNK; ++pp) {
        __syncthreads();   // previous compute done, safe to overwrite LDS
        #pragma unroll
        for (int j = 0; j < 6; ++j) {
            const int i = threadIdx.x + j*256;
            if (sidx[j] != -2) sT[(i/HT)*HS + (i - (i/HT)*HT)] = pf[j];
        }
        __syncthreads();
        if (pp + 1 < PCHUNK) {   // issue next tile's loads; latency hides under compute
            const float* ap = a + (size_t)((b*PP + p0 + pp + 1)*CC + c) * MN;
            #pragma unroll
            for (int j = 0; j < 6; ++j)
                if (sidx[j] != -2) pf[j] = (sidx[j] >= 0) ? ap[sidx[j]] : 0.f;
        }
        const float* bp = Bw + ((p0 + pp)*CC + c) * 49;
        #pragma unroll
        for (int u = 0; u < 7; ++u) {
            const int base = (row + u)*HS + tg*4;
            const float4 q0 = *(const float4*)&sT[base];
            const float4 q1 = *(const float4*)&sT[base + 4];
            const float2 q2 = *(const float2*)&sT[base + 8];
            const float rv[10] = {q0.x,q0.y,q0.z,q0.w,q1.x,q1.y,q1.z,q1.w,q2.x,q2.y};
            #pragma unroll
            for (int v = 0; v < 7; ++v) {
                const float bv = bp[u*7 + v];
                acc[0] += rv[v]   * bv;
                acc[1] += rv[v+1] * bv;
                acc[2] += rv[v+2] * bv;
                acc[3] += rv[v+3] * bv;
            }
        }
    }
    const int idx = (b*CC + c)*MN + (m0 + row)*NN + n0 + tg*4;
    float4 o; o.x = acc[0]; o.y = acc[1]; o.z = acc[2]; o.w = acc[3];
    *(float4*)&part[(size_t)s*IMG + idx] = o;
}

// a_out = soft(a_in + g2 * convT_csc(r, B), g2*lam1)  for p in chunk s
__global__ __launch_bounds__(256) void k_a_update(
    const float* __restrict__ a_in, const float* __restrict__ rr,
    const float* __restrict__ Bw, float* __restrict__ a_out,
    const float* __restrict__ gam2, const float* __restrict__ lam1, int k)
{
    const int bc = blockIdx.z % (MB*CC);
    const int s  = blockIdx.z / (MB*CC);
    const int b = bc / CC, c = bc % CC;
    const int m0 = blockIdx.y * TDIM, n0 = blockIdx.x * TDIM;
    const float g2  = gam2[k];
    const float thr = g2 * lam1[k];
    __shared__ float sT[HT * HS];
    const float* rp = rr + (b*CC + c)*MN;
    for (int i = threadIdx.x; i < HTT; i += 256) {
        const int im = i / HT, in = i - im*HT;
        const int gm = m0 + im - 3, gn = n0 + in - 3;
        float v = 0.f;
        if ((unsigned)gm < MM && (unsigned)gn < NN) v = rp[gm*NN + gn];
        sT[im*HS + in] = v;
    }
    __syncthreads();
    const int row = threadIdx.x >> 3;
    const int tg  = threadIdx.x & 7;
    const int gm = m0 + row;
    const int gn = n0 + tg*4;
    const int p0 = s * PCHUNK;
    for (int pp = 0; pp < PCHUNK; ++pp) {
        const int p = p0 + pp;
        const float* bp = Bw + (p*CC + c) * 49;
        float acc[4] = {0.f, 0.f, 0.f, 0.f};
        #pragma unroll
        for (int u = 0; u < 7; ++u) {
            const int base = (row + 6 - u)*HS + tg*4;
            const float4 q0 = *(const float4*)&sT[base];
            const float4 q1 = *(const float4*)&sT[base + 4];
            const float2 q2 = *(const float2*)&sT[base + 8];
            const float rv[10] = {q0.x,q0.y,q0.z,q0.w,q1.x,q1.y,q1.z,q1.w,q2.x,q2.y};
            #pragma unroll
            for (int v = 0; v < 7; ++v) {
                const float bv = bp[u*7 + v];
                acc[0] += rv[6-v] * bv;
                acc[1] += rv[7-v] * bv;
                acc[2] += rv[8-v] * bv;
                acc[3] += rv[9-v] * bv;
            }
        }
        const size_t idx = (size_t)((b*PP + p)*CC + c)*MN + gm*NN + gn;
        const float4 av = *(const float4*)&a_in[idx];
        float4 o;
        o.x = softf(av.x + g2*acc[0], thr);
        o.y = softf(av.y + g2*acc[1], thr);
        o.z = softf(av.z + g2*acc[2], thr);
        o.w = softf(av.w + g2*acc[3], thr);
        *(float4*)&a_out[idx] = o;
    }
}

// fold partials: r = xbef - sum(part); write rb; x_aft = clip(xbef - g1*(r + Ctop(Dtop(y1)) + mask*y2))
__global__ __launch_bounds__(256) void k_x_update(
    const float* __restrict__ xbef, const float* __restrict__ part,
    float* __restrict__ rb,
    const float* __restrict__ y1, const float* __restrict__ y2,
    const float* __restrict__ mask, const float* __restrict__ gam1, int k,
    float* __restrict__ xaft)
{
    const int i = blockIdx.x*256 + threadIdx.x;
    if (i >= MB*MN) return;
    const int b = i / MN, mn = i - b*MN;
    const int m = mn / NN, n = mn - m*NN;
    const float g1 = gam1[k];
    float dt[3];
    #pragma unroll
    for (int e = 0; e < 3; ++e) {
        const float* yv = y1 + ((size_t)(b*2 + 0)*CC + e)*MN;
        const float* yh = y1 + ((size_t)(b*2 + 1)*CC + e)*MN;
        float dv = (m > 0 ? yv[mn - NN] : 0.f) - (m < MM-1 ? yv[mn] : 0.f);
        float dh = (n > 0 ? yh[mn - 1]  : 0.f) - (n < NN-1 ? yh[mn] : 0.f);
        dt[e] = dv + dh;
    }
    const float ct0 = S3*dt[0] + S2*dt[1] + S6*dt[2];
    const float ct1 = S3*dt[0] - S2*dt[1] + S6*dt[2];
    const float ct2 = S3*dt[0]            - 2.f*S6*dt[2];
    const float ct[3] = {ct0, ct1, ct2};
    #pragma unroll
    for (int c = 0; c < 3; ++c) {
        const int idx = (b*CC + c)*MN + mn;
        const float conv = part[idx] + part[IMG + idx] + part[2*IMG + idx] + part[3*IMG + idx];
        const float r = xbef[idx] - conv;
        rb[idx] = r;
        float x = xbef[idx] - g1*(r + ct[c] + mask[idx]*y2[idx]);
        x = fminf(fmaxf(x, 0.f), 1.f);
        xaft[idx] = x;
    }
}

// y1 += g3*Dop(Cop(v)); y1 -= g3*prox_dvtv(y1/(g3+eps), lam2/(g3+eps), w)
__global__ __launch_bounds__(256) void k_y1_update(
    float* __restrict__ y1, const float* __restrict__ xaft,
    const float* __restrict__ xbef,
    const float* __restrict__ gam3, const float* __restrict__ lam2, int k)
{
    const int i = blockIdx.x*256 + threadIdx.x;
    if (i >= MB*MN) return;
    const int b = i / MN, mn = i - b*MN;
    const int m = mn / NN, n = mn - m*NN;
    const float g3  = gam3[k];
    const float inv = 1.f / (g3 + EPSV);
    const float t   = lam2[k] * inv;
    const bool hasD = (m < MM-1), hasR = (n < NN-1);
    float vc[3], vd[3], vr[3];
    #pragma unroll
    for (int c = 0; c < 3; ++c) {
        const int idx = (b*CC + c)*MN + mn;
        vc[c] = 2.f*xaft[idx] - xbef[idx];
        vd[c] = hasD ? (2.f*xaft[idx+NN] - xbef[idx+NN]) : 0.f;
        vr[c] = hasR ? (2.f*xaft[idx+1]  - xbef[idx+1])  : 0.f;
    }
    const float cc0 = S3*(vc[0]+vc[1]+vc[2]);
    const float cc1 = S2*(vc[0]-vc[1]);
    const float cc2 = S6*(vc[0]+vc[1]) - 2.f*S6*vc[2];
    const float cd0 = S3*(vd[0]+vd[1]+vd[2]);
    const float cd1 = S2*(vd[0]-vd[1]);
    const float cd2 = S6*(vd[0]+vd[1]) - 2.f*S6*vd[2];
    const float cr0 = S3*(vr[0]+vr[1]+vr[2]);
    const float cr1 = S2*(vr[0]-vr[1]);
    const float cr2 = S6*(vr[0]+vr[1]) - 2.f*S6*vr[2];
    const float dv[3] = { hasD ? cd0-cc0 : 0.f, hasD ? cd1-cc1 : 0.f, hasD ? cd2-cc2 : 0.f };
    const float dh[3] = { hasR ? cr0-cc0 : 0.f, hasR ? cr1-cc1 : 0.f, hasR ? cr2-cc2 : 0.f };
    float yn[2][3], vv[2][3];
    #pragma unroll
    for (int e = 0; e < 3; ++e) {
        const int i0 = ((b*2 + 0)*CC + e)*MN + mn;
        const int i1 = ((b*2 + 1)*CC + e)*MN + mn;
        yn[0][e] = y1[i0] + g3*dv[e];
        yn[1][e] = y1[i1] + g3*dh[e];
        vv[0][e] = yn[0][e]*inv;
        vv[1][e] = yn[1][e]*inv;
    }
    const float nl = sqrtf(vv[0][0]*vv[0][0] + vv[1][0]*vv[1][0]);
    const float sl = fmaxf(0.f, 1.f - t / fmaxf(nl, 1e-12f));
    const float nc = sqrtf(vv[0][1]*vv[0][1] + vv[0][2]*vv[0][2]
                         + vv[1][1]*vv[1][1] + vv[1][2]*vv[1][2]);
    const float sc = fmaxf(0.f, 1.f - t*W_CH / fmaxf(nc, 1e-12f));
    #pragma unroll
    for (int e = 0; e < 3; ++e) {
        const float se = (e == 0) ? sl : sc;
        const int i0 = ((b*2 + 0)*CC + e)*MN + mn;
        const int i1 = ((b*2 + 1)*CC + e)*MN + mn;
        y1[i0] = yn[0][e] - g3*(vv[0][e]*se);
        y1[i1] = yn[1][e] - g3*(vv[1][e]*se);
    }
}

// y2 += g3*mask*v; accumulate per-batch ||y2/(g3+eps) - z||^2
__global__ __launch_bounds__(256) void k_y2_acc(
    float* __restrict__ y2, const float* __restrict__ xaft,
    const float* __restrict__ xbef, const float* __restrict__ mask,
    const float* __restrict__ z,
    const float* __restrict__ gam3, int k, float* __restrict__ sums)
{
    const int i = blockIdx.x*256 + threadIdx.x;
    const float g3  = gam3[k];
    const float inv = 1.f / (g3 + EPSV);
    float dsq = 0.f;
    if (i < IMG) {
        const float v  = 2.f*xaft[i] - xbef[i];
        const float yn = y2[i] + g3*(mask[i]*v);
        y2[i] = yn;
        const float d = yn*inv - z[i];
        dsq = d*d;
    }
    #pragma unroll
    for (int off = 32; off > 0; off >>= 1) dsq += __shfl_down(dsq, off, 64);
    if ((threadIdx.x & 63) == 0) {
        const int b = blockIdx.x / (CMN/256);
        atomicAdd(&sums[b], dsq);
    }
}

// y2 -= g3 * proj_l2ball(y2/(g3+eps), z, radius)
__global__ __launch_bounds__(256) void k_y2_proj(
    float* __restrict__ y2, const float* __restrict__ z,
    const float* __restrict__ gam3, int k, const float* __restrict__ sums)
{
    const int i = blockIdx.x*256 + threadIdx.x;
    if (i >= IMG) return;
    const float g3  = gam3[k];
    const float inv = 1.f / (g3 + EPSV);
    const int b = blockIdx.x / (CMN/256);
    const float nrm = sqrtf(sums[b]);
    const float scale = fminf(1.f, RADIUS / fmaxf(nrm, 1e-12f));
    const float zi = z[i];
    const float d = y2[i]*inv - zi;
    y2[i] = y2[i] - g3*(zi + d*scale);
}

extern "C" void kernel_launch(void* const* d_in, const int* in_sizes, int n_in,
                              void* d_out, int out_size, void* d_ws, size_t ws_size,
                              hipStream_t stream) {
    const float* z    = (const float*)d_in[0];
    const float* mask = (const float*)d_in[1];
    const float* a0   = (const float*)d_in[2];
    const float* Bw   = (const float*)d_in[3];
    const float* lam1 = (const float*)d_in[4];
    const float* lam2 = (const float*)d_in[5];
    const float* gam1 = (const float*)d_in[6];
    const float* gam2 = (const float*)d_in[7];
    const float* gam3 = (const float*)d_in[8];
    float* out = (float*)d_out;

    float* ws = (float*)d_ws;
    float* xA   = ws; ws += IMG;
    float* xB   = ws; ws += IMG;
    float* y1   = ws; ws += 2*IMG;
    float* y2   = ws; ws += IMG;
    float* rb   = ws; ws += IMG;
    float* part = ws; ws += PSPLIT*IMG;
    float* sums = ws; ws += 64;
    const size_t base_need = (size_t)((6 + PSPLIT)*IMG + 64) * sizeof(float);
    float* a_ws;
    if (ws_size >= base_need + (size_t)ASZ * sizeof(float)) {
        a_ws = ws;                    // normal: a lives in workspace
    } else {
        a_ws = (float*)d_in[2];       // fallback: in-place on a0 (restored per launch)
    }

    hipMemsetAsync(y1, 0, sizeof(float)*2*IMG, stream);
    hipMemsetAsync(y2, 0, sizeof(float)*IMG, stream);

    dim3 gconv(NN/TDIM, MM/TDIM, MB*CC*PSPLIT);   // 6 x 6 x 48 = 1728 blocks
    const int ew_blocks  = (MB*MN + 255) / 256;   // 576
    const int img_blocks = IMG / 256;             // 1728

    const float* xbef = z;
    float* xaft = xA;
    const float* acur = a0;
    for (int k = 0; k < KITER; ++k) {
        k_conv_part<<<gconv, 256, 0, stream>>>(acur, Bw, part);
        float* xt = (k == KITER-1) ? out : xaft;
        k_x_update<<<ew_blocks, 256, 0, stream>>>(xbef, part, rb, y1, y2, mask, gam1, k, xt);
        if (k < KITER-1) {
            k_a_update<<<gconv, 256, 0, stream>>>(acur, rb, Bw, a_ws, gam2, lam1, k);
            k_y1_update<<<ew_blocks, 256, 0, stream>>>(y1, xt, xbef, gam3, lam2, k);
            hipMemsetAsync(sums, 0, sizeof(float)*4, stream);
            k_y2_acc<<<img_blocks, 256, 0, stream>>>(y2, xt, xbef, mask, z, gam3, k, sums);
            k_y2_proj<<<img_blocks, 256, 0, stream>>>(y2, z, gam3, k, sums);
            acur = a_ws;
            xbef = xt;
            xaft = (xt == xA) ? xB : xA;
        }
    }
    (void)in_sizes; (void)n_in; (void)out_size;
}

// Round 3
// 925.329 us; speedup vs baseline: 2.2748x; 1.6938x over previous
//
#include <hip/hip_runtime.h>

#define MB 4
#define CC 3
#define MM 192
#define NN 192
#define PP 32
#define KITER 8
#define MN (MM*NN)          /* 36864  */
#define CMN (CC*MN)         /* 110592 */
#define IMG (MB*CMN)        /* 442368 */
#define ASZ (MB*PP*CMN)     /* 14155776 */

#define PSPLIT 4
#define PCHUNK (PP/PSPLIT)  /* 8 */

#define S3 0.57735026918962576f
#define S2 0.70710678118654752f
#define S6 0.40824829046386302f
#define W_CH 0.8f
#define EPSV 1e-8f
#define RADIUS 6.6510751010644885f   /* 0.02*sqrt(3*192*192) */

#define TDIM 32
#define HT 38       /* tile + 6 halo */
#define HS 40       /* padded LDS row stride */
#define HTT (HT*HT) /* 1444 */

__device__ __forceinline__ float softf(float x, float t) {
    float m = fabsf(x) - t;
    return m > 0.f ? copysignf(m, x) : 0.f;
}

// partial conv: part[s] = sum_{p in chunk s} xcorr(a[b,p,c], B[p,c])
__global__ __launch_bounds__(256) void k_conv_part(
    const float* __restrict__ a, const float* __restrict__ Bw,
    float* __restrict__ part)
{
    const int bc = blockIdx.z % (MB*CC);
    const int s  = blockIdx.z / (MB*CC);
    const int b = bc / CC, c = bc % CC;
    const int m0 = blockIdx.y * TDIM, n0 = blockIdx.x * TDIM;
    __shared__ float sT[HT * HS];
    const int row = threadIdx.x >> 3;      // 0..31
    const int tg  = threadIdx.x & 7;       // 0..7 -> cols tg*4..+3
    float acc[4] = {0.f, 0.f, 0.f, 0.f};
    const int p0 = s * PCHUNK;

    int   sidx[6]; float pf[6];
    #pragma unroll
    for (int j = 0; j < 6; ++j) {
        const int i = threadIdx.x + j*256;
        if (i < HTT) {
            const int im = i / HT, in = i - im*HT;
            const int gm = m0 + im - 3, gn = n0 + in - 3;
            sidx[j] = ((unsigned)gm < MM && (unsigned)gn < NN) ? (gm*NN + gn) : -1;
        } else sidx[j] = -2;
    }
    {
        const float* ap = a + (size_t)((b*PP + p0)*CC + c) * MN;
        #pragma unroll
        for (int j = 0; j < 6; ++j)
            if (sidx[j] != -2) pf[j] = (sidx[j] >= 0) ? ap[sidx[j]] : 0.f;
    }
    for (int pp = 0; pp < PCHUNK; ++pp) {
        __syncthreads();
        #pragma unroll
        for (int j = 0; j < 6; ++j) {
            const int i = threadIdx.x + j*256;
            if (sidx[j] != -2) sT[(i/HT)*HS + (i - (i/HT)*HT)] = pf[j];
        }
        __syncthreads();
        if (pp + 1 < PCHUNK) {
            const float* ap = a + (size_t)((b*PP + p0 + pp + 1)*CC + c) * MN;
            #pragma unroll
            for (int j = 0; j < 6; ++j)
                if (sidx[j] != -2) pf[j] = (sidx[j] >= 0) ? ap[sidx[j]] : 0.f;
        }
        const float* bp = Bw + ((p0 + pp)*CC + c) * 49;
        #pragma unroll
        for (int u = 0; u < 7; ++u) {
            const int base = (row + u)*HS + tg*4;
            const float4 q0 = *(const float4*)&sT[base];
            const float4 q1 = *(const float4*)&sT[base + 4];
            const float2 q2 = *(const float2*)&sT[base + 8];
            const float rv[10] = {q0.x,q0.y,q0.z,q0.w,q1.x,q1.y,q1.z,q1.w,q2.x,q2.y};
            #pragma unroll
            for (int v = 0; v < 7; ++v) {
                const float bv = bp[u*7 + v];
                acc[0] += rv[v]   * bv;
                acc[1] += rv[v+1] * bv;
                acc[2] += rv[v+2] * bv;
                acc[3] += rv[v+3] * bv;
            }
        }
    }
    const int idx = (b*CC + c)*MN + (m0 + row)*NN + n0 + tg*4;
    float4 o; o.x = acc[0]; o.y = acc[1]; o.z = acc[2]; o.w = acc[3];
    *(float4*)&part[(size_t)s*IMG + idx] = o;
}

// a_out = soft(a_in + g2 * convT_csc(r, B), g2*lam1)  for p in chunk s
__global__ __launch_bounds__(256) void k_a_update(
    const float* __restrict__ a_in, const float* __restrict__ rr,
    const float* __restrict__ Bw, float* __restrict__ a_out,
    const float* __restrict__ gam2, const float* __restrict__ lam1, int k)
{
    const int bc = blockIdx.z % (MB*CC);
    const int s  = blockIdx.z / (MB*CC);
    const int b = bc / CC, c = bc % CC;
    const int m0 = blockIdx.y * TDIM, n0 = blockIdx.x * TDIM;
    const float g2  = gam2[k];
    const float thr = g2 * lam1[k];
    __shared__ float sT[HT * HS];
    const float* rp = rr + (b*CC + c)*MN;
    for (int i = threadIdx.x; i < HTT; i += 256) {
        const int im = i / HT, in = i - im*HT;
        const int gm = m0 + im - 3, gn = n0 + in - 3;
        float v = 0.f;
        if ((unsigned)gm < MM && (unsigned)gn < NN) v = rp[gm*NN + gn];
        sT[im*HS + in] = v;
    }
    __syncthreads();
    const int row = threadIdx.x >> 3;
    const int tg  = threadIdx.x & 7;
    const int gm = m0 + row;
    const int gn = n0 + tg*4;
    const int p0 = s * PCHUNK;
    for (int pp = 0; pp < PCHUNK; ++pp) {
        const int p = p0 + pp;
        const float* bp = Bw + (p*CC + c) * 49;
        float acc[4] = {0.f, 0.f, 0.f, 0.f};
        #pragma unroll
        for (int u = 0; u < 7; ++u) {
            const int base = (row + 6 - u)*HS + tg*4;
            const float4 q0 = *(const float4*)&sT[base];
            const float4 q1 = *(const float4*)&sT[base + 4];
            const float2 q2 = *(const float2*)&sT[base + 8];
            const float rv[10] = {q0.x,q0.y,q0.z,q0.w,q1.x,q1.y,q1.z,q1.w,q2.x,q2.y};
            #pragma unroll
            for (int v = 0; v < 7; ++v) {
                const float bv = bp[u*7 + v];
                acc[0] += rv[6-v] * bv;
                acc[1] += rv[7-v] * bv;
                acc[2] += rv[8-v] * bv;
                acc[3] += rv[9-v] * bv;
            }
        }
        const size_t idx = (size_t)((b*PP + p)*CC + c)*MN + gm*NN + gn;
        const float4 av = *(const float4*)&a_in[idx];
        float4 o;
        o.x = softf(av.x + g2*acc[0], thr);
        o.y = softf(av.y + g2*acc[1], thr);
        o.z = softf(av.z + g2*acc[2], thr);
        o.w = softf(av.w + g2*acc[3], thr);
        *(float4*)&a_out[idx] = o;
    }
}

// Fused: lazy y2 projection (iter k-1) + fold conv partials + x update +
//        y2 accumulation + per-batch norm reduction (one atomic/block).
// sums layout: sums[k*64 + b*16]  (64B-padded per batch, per iteration)
__global__ __launch_bounds__(256) void k_x_update(
    const float* __restrict__ xbef, const float* __restrict__ part,
    float* __restrict__ rb,
    const float* __restrict__ y1, float* __restrict__ y2,
    const float* __restrict__ mask, const float* __restrict__ z,
    const float* __restrict__ gam1, const float* __restrict__ gam3, int k,
    float* __restrict__ xaft, float* __restrict__ sums)
{
    const int i = blockIdx.x*256 + threadIdx.x;   // grid exactly covers MB*MN
    const int b = i / MN, mn = i - b*MN;
    const int m = mn / NN, n = mn - m*NN;
    const float g1 = gam1[k];
    const float g3 = gam3[k];
    const float inv3 = 1.f / (g3 + EPSV);
    float g3p = 0.f, invp = 0.f, scale_prev = 0.f;
    if (k > 0) {
        g3p  = gam3[k-1];
        invp = 1.f / (g3p + EPSV);
        const float nrm = sqrtf(sums[(k-1)*64 + b*16]);
        scale_prev = fminf(1.f, RADIUS / fmaxf(nrm, 1e-12f));
    }
    float dt[3];
    #pragma unroll
    for (int e = 0; e < 3; ++e) {
        const float* yv = y1 + ((size_t)(b*2 + 0)*CC + e)*MN;
        const float* yh = y1 + ((size_t)(b*2 + 1)*CC + e)*MN;
        float dv = (m > 0 ? yv[mn - NN] : 0.f) - (m < MM-1 ? yv[mn] : 0.f);
        float dh = (n > 0 ? yh[mn - 1]  : 0.f) - (n < NN-1 ? yh[mn] : 0.f);
        dt[e] = dv + dh;
    }
    const float ct0 = S3*dt[0] + S2*dt[1] + S6*dt[2];
    const float ct1 = S3*dt[0] - S2*dt[1] + S6*dt[2];
    const float ct2 = S3*dt[0]            - 2.f*S6*dt[2];
    const float ct[3] = {ct0, ct1, ct2};
    const bool last = (k == KITER-1);
    float dsq = 0.f;
    #pragma unroll
    for (int c = 0; c < 3; ++c) {
        const int idx = (b*CC + c)*MN + mn;
        const float conv = part[idx] + part[IMG + idx] + part[2*IMG + idx] + part[3*IMG + idx];
        const float xb = xbef[idx];
        const float r = xb - conv;
        const float zi = z[idx];
        const float mk = mask[idx];
        float y2b = 0.f;
        if (k > 0) {   // lazily apply iter-(k-1) L2-ball projection
            const float yr = y2[idx];
            const float d = yr*invp - zi;
            y2b = yr - g3p*(zi + d*scale_prev);
        }
        float x = xb - g1*(r + ct[c] + mk*y2b);
        x = fminf(fmaxf(x, 0.f), 1.f);
        xaft[idx] = x;
        if (!last) {
            rb[idx] = r;
            const float v  = 2.f*x - xb;
            const float yn = y2b + g3*(mk*v);
            y2[idx] = yn;               // post-acc, pre-proj (proj applied lazily next iter)
            const float d2 = yn*inv3 - zi;
            dsq += d2*d2;
        }
    }
    if (!last) {
        #pragma unroll
        for (int off = 32; off > 0; off >>= 1) dsq += __shfl_down(dsq, off, 64);
        __shared__ float red[4];
        if ((threadIdx.x & 63) == 0) red[threadIdx.x >> 6] = dsq;
        __syncthreads();
        if (threadIdx.x == 0)
            atomicAdd(&sums[k*64 + b*16], red[0] + red[1] + red[2] + red[3]);
    }
}

// y1 += g3*Dop(Cop(v)); y1 -= g3*prox_dvtv(y1/(g3+eps), lam2/(g3+eps), w)
__global__ __launch_bounds__(256) void k_y1_update(
    float* __restrict__ y1, const float* __restrict__ xaft,
    const float* __restrict__ xbef,
    const float* __restrict__ gam3, const float* __restrict__ lam2, int k)
{
    const int i = blockIdx.x*256 + threadIdx.x;
    if (i >= MB*MN) return;
    const int b = i / MN, mn = i - b*MN;
    const int m = mn / NN, n = mn - m*NN;
    const float g3  = gam3[k];
    const float inv = 1.f / (g3 + EPSV);
    const float t   = lam2[k] * inv;
    const bool hasD = (m < MM-1), hasR = (n < NN-1);
    float vc[3], vd[3], vr[3];
    #pragma unroll
    for (int c = 0; c < 3; ++c) {
        const int idx = (b*CC + c)*MN + mn;
        vc[c] = 2.f*xaft[idx] - xbef[idx];
        vd[c] = hasD ? (2.f*xaft[idx+NN] - xbef[idx+NN]) : 0.f;
        vr[c] = hasR ? (2.f*xaft[idx+1]  - xbef[idx+1])  : 0.f;
    }
    const float cc0 = S3*(vc[0]+vc[1]+vc[2]);
    const float cc1 = S2*(vc[0]-vc[1]);
    const float cc2 = S6*(vc[0]+vc[1]) - 2.f*S6*vc[2];
    const float cd0 = S3*(vd[0]+vd[1]+vd[2]);
    const float cd1 = S2*(vd[0]-vd[1]);
    const float cd2 = S6*(vd[0]+vd[1]) - 2.f*S6*vd[2];
    const float cr0 = S3*(vr[0]+vr[1]+vr[2]);
    const float cr1 = S2*(vr[0]-vr[1]);
    const float cr2 = S6*(vr[0]+vr[1]) - 2.f*S6*vr[2];
    const float dv[3] = { hasD ? cd0-cc0 : 0.f, hasD ? cd1-cc1 : 0.f, hasD ? cd2-cc2 : 0.f };
    const float dh[3] = { hasR ? cr0-cc0 : 0.f, hasR ? cr1-cc1 : 0.f, hasR ? cr2-cc2 : 0.f };
    float yn[2][3], vv[2][3];
    #pragma unroll
    for (int e = 0; e < 3; ++e) {
        const int i0 = ((b*2 + 0)*CC + e)*MN + mn;
        const int i1 = ((b*2 + 1)*CC + e)*MN + mn;
        yn[0][e] = y1[i0] + g3*dv[e];
        yn[1][e] = y1[i1] + g3*dh[e];
        vv[0][e] = yn[0][e]*inv;
        vv[1][e] = yn[1][e]*inv;
    }
    const float nl = sqrtf(vv[0][0]*vv[0][0] + vv[1][0]*vv[1][0]);
    const float sl = fmaxf(0.f, 1.f - t / fmaxf(nl, 1e-12f));
    const float nc = sqrtf(vv[0][1]*vv[0][1] + vv[0][2]*vv[0][2]
                         + vv[1][1]*vv[1][1] + vv[1][2]*vv[1][2]);
    const float sc = fmaxf(0.f, 1.f - t*W_CH / fmaxf(nc, 1e-12f));
    #pragma unroll
    for (int e = 0; e < 3; ++e) {
        const float se = (e == 0) ? sl : sc;
        const int i0 = ((b*2 + 0)*CC + e)*MN + mn;
        const int i1 = ((b*2 + 1)*CC + e)*MN + mn;
        y1[i0] = yn[0][e] - g3*(vv[0][e]*se);
        y1[i1] = yn[1][e] - g3*(vv[1][e]*se);
    }
}

extern "C" void kernel_launch(void* const* d_in, const int* in_sizes, int n_in,
                              void* d_out, int out_size, void* d_ws, size_t ws_size,
                              hipStream_t stream) {
    const float* z    = (const float*)d_in[0];
    const float* mask = (const float*)d_in[1];
    const float* a0   = (const float*)d_in[2];
    const float* Bw   = (const float*)d_in[3];
    const float* lam1 = (const float*)d_in[4];
    const float* lam2 = (const float*)d_in[5];
    const float* gam1 = (const float*)d_in[6];
    const float* gam2 = (const float*)d_in[7];
    const float* gam3 = (const float*)d_in[8];
    float* out = (float*)d_out;

    float* ws = (float*)d_ws;
    float* xA   = ws; ws += IMG;
    float* xB   = ws; ws += IMG;
    float* y1   = ws; ws += 2*IMG;
    float* y2   = ws; ws += IMG;
    float* rb   = ws; ws += IMG;
    float* part = ws; ws += PSPLIT*IMG;
    float* sums = ws; ws += KITER*64;
    const size_t base_need = (size_t)((6 + PSPLIT)*IMG + KITER*64) * sizeof(float);
    float* a_ws;
    if (ws_size >= base_need + (size_t)ASZ * sizeof(float)) {
        a_ws = ws;                    // normal: a lives in workspace
    } else {
        a_ws = (float*)d_in[2];       // fallback: in-place on a0 (restored per launch)
    }

    hipMemsetAsync(y1, 0, sizeof(float)*2*IMG, stream);
    hipMemsetAsync(sums, 0, sizeof(float)*KITER*64, stream);
    // y2 needs no init: k==0 treats y2_bef as 0 and overwrites.

    dim3 gconv(NN/TDIM, MM/TDIM, MB*CC*PSPLIT);   // 6 x 6 x 48 = 1728 blocks
    const int ew_blocks = (MB*MN) / 256;          // 576 (exact)

    const float* xbef = z;
    float* xaft = xA;
    const float* acur = a0;
    for (int k = 0; k < KITER; ++k) {
        k_conv_part<<<gconv, 256, 0, stream>>>(acur, Bw, part);
        float* xt = (k == KITER-1) ? out : xaft;
        k_x_update<<<ew_blocks, 256, 0, stream>>>(xbef, part, rb, y1, y2, mask, z,
                                                  gam1, gam3, k, xt, sums);
        if (k < KITER-1) {
            k_a_update<<<gconv, 256, 0, stream>>>(acur, rb, Bw, a_ws, gam2, lam1, k);
            k_y1_update<<<ew_blocks, 256, 0, stream>>>(y1, xt, xbef, gam3, lam2, k);
            acur = a_ws;
            xbef = xt;
            xaft = (xt == xA) ? xB : xA;
        }
    }
    (void)in_sizes; (void)n_in; (void)out_size;
}